// Round 8
// baseline (736.615 us; speedup 1.0000x reference)
//
#include <hip/hip_runtime.h>
#include <cstdint>
#include <cstddef>

#define D_HEAD   64
#define NHEAD    16
#define DMODEL   1024
#define SLEN     2048
#define BSZ      4
#define MROWS    (SLEN*BSZ)            // 8192
#define NQKVB    (NHEAD*(3*D_HEAD+1))  // 3088
#define NQPAD    3200                  // padded to 25*128 for the 128-tile GEMM
#define EPSV     1e-5f
#define SCALEV   0.125f                // 1/sqrt(64)
#define GQ8      8                     // recurrence lookahead group
#define NG8      (SLEN/GQ8)            // 256

typedef short bf16x8 __attribute__((ext_vector_type(8)));
typedef float f32x4  __attribute__((ext_vector_type(4)));

__device__ __forceinline__ unsigned short f2bf(float f){
  unsigned int u = __float_as_uint(f);
  u = (u + 0x7fffu + ((u >> 16) & 1u)) >> 16;   // RNE
  return (unsigned short)u;
}
__device__ __forceinline__ float bf2f(unsigned short s){
  return __uint_as_float(((unsigned int)s) << 16);
}

__device__ __forceinline__ void gload_lds16(const unsigned short* g, unsigned short* l){
  __builtin_amdgcn_global_load_lds((const __attribute__((address_space(1))) void*)g,
                                   (__attribute__((address_space(3))) void*)l, 16, 0, 0);
}
__device__ __forceinline__ void gload16f(const float* g, float* l){
  __builtin_amdgcn_global_load_lds((const __attribute__((address_space(1))) void*)g,
                                   (__attribute__((address_space(3))) void*)l, 16, 0, 0);
}

// ------------------------------------------------------------------ cast
__global__ void cast_bf16_kernel(const float* __restrict__ src,
                                 unsigned short* __restrict__ dst, int n4){
  int stride = gridDim.x * blockDim.x;
  for (int i = blockIdx.x*blockDim.x + threadIdx.x; i < n4; i += stride){
    float4 f = ((const float4*)src)[i];
    ushort4 u;
    u.x = f2bf(f.x); u.y = f2bf(f.y); u.z = f2bf(f.z); u.w = f2bf(f.w);
    ((ushort4*)dst)[i] = u;
  }
}

// ------------------------------------------------------------------ GEMM (NT), m97 structure
template<bool OUT_BF16>
__global__ __launch_bounds__(256) void gemm_big_kernel(
    const unsigned short* __restrict__ A, const unsigned short* __restrict__ B,
    void* __restrict__ C, int M, int N, int K){
  __shared__ __align__(16) unsigned short sA[128*32];
  __shared__ __align__(16) unsigned short sB[128*32];
  int m0 = blockIdx.x * 128, n0 = blockIdx.y * 128;
  int tid = threadIdx.x;
  int wv = tid >> 6, ln = tid & 63;
  int lm = ln & 15, quad = ln >> 4;
  int wm = (wv >> 1) * 64, wn = (wv & 1) * 64;
  f32x4 acc[4][4] = {};

  for (int kt = 0; kt < K; kt += 32){
    __syncthreads();
    #pragma unroll
    for (int it = 0; it < 2; ++it){
      int s = wv*128 + it*64 + ln;          // 0..511
      int row = s >> 2, sg = s & 3;
      gload_lds16(A + (size_t)(m0+row)*K + kt + sg*8, sA + (size_t)(wv*128 + it*64)*8);
      gload_lds16(B + (size_t)(n0+row)*K + kt + sg*8, sB + (size_t)(wv*128 + it*64)*8);
    }
    __syncthreads();
    bf16x8 af[4], bfr[4];
    #pragma unroll
    for (int i = 0; i < 4; ++i){
      af[i]  = *(const bf16x8*)(sA + ((wm + i*16 + lm)*32 + quad*8));
      bfr[i] = *(const bf16x8*)(sB + ((wn + i*16 + lm)*32 + quad*8));
    }
    #pragma unroll
    for (int mi = 0; mi < 4; ++mi)
      #pragma unroll
      for (int ni = 0; ni < 4; ++ni)
        acc[mi][ni] = __builtin_amdgcn_mfma_f32_16x16x32_bf16(af[mi], bfr[ni], acc[mi][ni], 0, 0, 0);
  }

  #pragma unroll
  for (int mi = 0; mi < 4; ++mi){
    int rowm = m0 + wm + mi*16 + quad*4;
    #pragma unroll
    for (int ni = 0; ni < 4; ++ni){
      int col = n0 + wn + ni*16 + lm;
      size_t cb = (size_t)rowm * N + col;
      #pragma unroll
      for (int rr = 0; rr < 4; ++rr){
        float v = acc[mi][ni][rr];
        if (OUT_BF16) ((unsigned short*)C)[cb + (size_t)rr*N] = f2bf(v);
        else          ((float*)C)[cb + (size_t)rr*N] = v;
      }
    }
  }
}

// ------------------------------------------------------------------ preprocess
__global__ __launch_bounds__(256) void prep_kernel(
    const unsigned short* __restrict__ qkvb,
    float* __restrict__ qb, float* __restrict__ kb, float* __restrict__ vb,
    float4* __restrict__ scal){
  int gid = blockIdx.x*4 + (threadIdx.x >> 6);   // m*16 + h
  int ln  = threadIdx.x & 63;
  int m = gid >> 4, h = gid & 15;
  size_t rb = (size_t)m * NQPAD + (size_t)h * 193;
  float qr = bf2f(qkvb[rb + ln]);
  float kr = bf2f(qkvb[rb + 64 + ln]);
  float vr = bf2f(qkvb[rb + 128 + ln]);
  float br = bf2f(qkvb[rb + 192]);
  float q1 = qr > 0.f ? qr + 1.f : __expf(qr);   // elu(x)+1
  float k1 = kr > 0.f ? kr + 1.f : __expf(kr);
  float sq = q1, sk = k1;
  #pragma unroll
  for (int off = 1; off < 64; off <<= 1){
    sq += __shfl_xor(sq, off, 64);
    sk += __shfl_xor(sk, off, 64);
  }
  float qn = q1 / sq, kn = k1 / sk;
  int b = m & 3, t = m >> 2;
  int bh = b*16 + h;
  size_t o = ((size_t)bh*SLEN + t)*64 + ln;
  qb[o] = qn; kb[o] = kn; vb[o] = vr;
  if (ln == 0){
    float sb = 1.f / (1.f + __expf(-br));
    scal[(size_t)bh*SLEN + t] = make_float4(0.f, 0.f, 0.f, sb);
  }
}

// ------------------------------------------------------------------ segmented cumsum over l
#define NSEG 16
#define SEGL (SLEN/NSEG)   // 128
__global__ __launch_bounds__(64) void segsum_kernel(
    const float* __restrict__ kb, float* __restrict__ S){
  int bh = blockIdx.x, seg = blockIdx.y, ln = threadIdx.x;
  size_t base = ((size_t)bh*SLEN + (size_t)seg*SEGL)*64 + ln;
  float s = 0.f;
  #pragma unroll 4
  for (int t = 0; t < SEGL; ++t) s += kb[base + (size_t)t*64];
  S[((size_t)bh*NSEG + seg)*64 + ln] = s;
}
__global__ __launch_bounds__(64) void scan_kernel(
    const float* __restrict__ kb, const float* __restrict__ S,
    float* __restrict__ Ab){
  int bh = blockIdx.x, seg = blockIdx.y, ln = threadIdx.x;
  float acc = 0.f;
  for (int s = 0; s < seg; ++s) acc += S[((size_t)bh*NSEG + s)*64 + ln];
  size_t base = ((size_t)bh*SLEN + (size_t)seg*SEGL)*64 + ln;
  #pragma unroll 4
  for (int t = 0; t < SEGL; ++t){
    acc += kb[base + (size_t)t*64];
    Ab[base + (size_t)t*64] = acc;
  }
}

// ------------------------------------------------------------------ denominators
// scal = {beta*kd, <kf,q>, SCALEV/(den+eps), -}; kb <- kf = kn/(kd+eps)
__global__ __launch_bounds__(256) void kden_kernel(
    const float* __restrict__ Ab, float* __restrict__ kb,
    const float* __restrict__ qb, float4* __restrict__ scal){
  int gid = blockIdx.x*4 + (threadIdx.x >> 6);   // bh*2048 + t
  int ln  = threadIdx.x & 63;
  int t = gid & (SLEN-1);
  size_t o = (size_t)gid*64 + ln;
  float a = Ab[o], kn = kb[o], qn = qb[o];
  float d0 = (a - kn)*kn, d1 = a*qn, d2 = kn*qn;
  #pragma unroll
  for (int off = 1; off < 64; off <<= 1){
    d0 += __shfl_xor(d0, off, 64);
    d1 += __shfl_xor(d1, off, 64);
    d2 += __shfl_xor(d2, off, 64);
  }
  float kd  = (t == 0) ? 1.f : d0;
  float inv = 1.f / (kd + EPSV);
  kb[o] = kn * inv;
  if (ln == 0){
    float4 s = scal[gid];
    scal[gid] = make_float4(s.w * kd, d2 * inv, SCALEV/(d1 + EPSV), 0.f);
  }
}

// ------------------------------------------------------------------ DPP helpers
template<int CTRL>
__device__ __forceinline__ float dpp_add(float x){
  return x + __int_as_float(__builtin_amdgcn_mov_dpp(__float_as_int(x), CTRL, 0xF, 0xF, true));
}
__device__ __forceinline__ float red16(float x){       // allreduce within 16-lane row
  x = dpp_add<0xB1>(x);    // quad_perm [1,0,3,2]
  x = dpp_add<0x4E>(x);    // quad_perm [2,3,0,1]
  x = dpp_add<0x124>(x);   // row_ror:4
  x = dpp_add<0x128>(x);   // row_ror:8
  return x;
}
__device__ __forceinline__ float red64_tail(float x){  // wave sum, valid in lane 63
  x = dpp_add<0x111>(x);   // row_shr:1
  x = dpp_add<0x112>(x);   // row_shr:2
  x = dpp_add<0x114>(x);   // row_shr:4
  x = dpp_add<0x118>(x);   // row_shr:8
  x = dpp_add<0x142>(x);   // row_bcast:15
  x = dpp_add<0x143>(x);   // row_bcast:31
  return x;
}

// pair index for i<j in [0,8)
__device__ __forceinline__ constexpr int PIDX(int i, int j){
  return 7*i - (i*(i-1))/2 + (j - i - 1);   // 0..27
}

// ------------------------------------------------------------------ pairwise dots (GQ8=8)
// one wave per (bh, group T of 8 steps); lane = d. Writes 56 floats per group
// (28 kk_ij then 28 kq_ij, i<j), padded to 16 float4.
__global__ __launch_bounds__(256) void pairdot_kernel(
    const float* __restrict__ kb, const float* __restrict__ qb,
    float4* __restrict__ pair){
  int gid = blockIdx.x*4 + (threadIdx.x >> 6);   // bh*NG8 + T
  int ln  = threadIdx.x & 63;
  size_t base = (size_t)gid*512 + ln;
  float k[8], q[8];
  #pragma unroll
  for (int i = 0; i < 8; ++i) k[i] = kb[base + i*64];
  #pragma unroll
  for (int i = 1; i < 8; ++i) q[i] = qb[base + i*64];
  float res[56];
  #pragma unroll
  for (int i = 0; i < 8; ++i)
    #pragma unroll
    for (int j = i+1; j < 8; ++j)
      res[PIDX(i,j)] = red64_tail(k[i]*k[j]);
  #pragma unroll
  for (int i = 0; i < 8; ++i)
    #pragma unroll
    for (int j = i+1; j < 8; ++j)
      res[28 + PIDX(i,j)] = red64_tail(k[i]*q[j]);
  if (ln == 63){
    float4* dst = pair + (size_t)gid*16;
    #pragma unroll
    for (int i = 0; i < 14; ++i)
      dst[i] = make_float4(res[i*4], res[i*4+1], res[i*4+2], res[i*4+3]);
  }
}

// ------------------------------------------------------------------ delta-rule recurrence, rank-8 groups, LDS-DMA dbuf
// grid (64 bh, 16 row-groups), 64 threads = 4 rows x 16 col-groups.
// lane: r = grp*4 + (ln>>4) owns W[r][c*4..c*4+4), c = ln&15.
// Per group: async global_load_lds of next group's tiles into alternate LDS
// buffer (no VGPR cost, can't be sunk), compute current group from LDS.
// LDS buffer layout (floats): k[8][64] @0, q[8][64] @512, v[8][64] @1024,
// scal[8][4] @1536, pair[64] @1568.  6528 B x 2.
#define DOT4(a,b) ((a).x*(b).x + (a).y*(b).y + (a).z*(b).z + (a).w*(b).w)

__global__ __launch_bounds__(64, 1) void recur_kernel(
    const float* __restrict__ kb, const float* __restrict__ qb,
    const float* __restrict__ vb, const float4* __restrict__ scal,
    const float4* __restrict__ pair, unsigned short* __restrict__ lo){
  __shared__ __align__(16) float sbuf[2][1632];
  int bh = blockIdx.x;
  int grp = blockIdx.y;
  int ln = threadIdx.x;
  int c  = ln & 15;
  int r  = grp*4 + (ln >> 4);
  size_t base = (size_t)bh * SLEN * 64;
  const float* kg = kb + base;
  const float* qg = qb + base;
  const float* vg = vb + base;
  const float* sgf = (const float*)(scal + (size_t)bh * SLEN);
  const float* pgf = (const float*)(pair + (size_t)bh * NG8 * 16);
  unsigned short* lop = lo + (size_t)(bh>>4)*DMODEL + (size_t)(bh&15)*64 + r;

  float4 W = {0,0,0,0};

  auto dma = [&](int T, float* B){
    int t0 = T*GQ8;
    #pragma unroll
    for (int i = 0; i < 2; ++i){
      int s = i*64 + ln;
      gload16f(kg + (size_t)(t0 + (s>>4))*64 + (s&15)*4, B + i*256);
      gload16f(qg + (size_t)(t0 + (s>>4))*64 + (s&15)*4, B + 512 + i*256);
      gload16f(vg + (size_t)(t0 + i*4 + (ln>>4))*64 + (ln&15)*4, B + 1024 + i*256);
    }
    if (ln < 8)  gload16f(sgf + (size_t)(t0 + ln)*4, B + 1536);
    if (ln < 16) gload16f(pgf + (size_t)T*64 + ln*4, B + 1568);
  };

  auto compute = [&](int T, const float* B){
    float4 karr[8];
    float m[8], p[8], vv[8];
    float4 sc[8];
    #pragma unroll
    for (int t = 0; t < 8; ++t){
      float4 kt = *(const float4*)(B + t*64 + c*4);
      float4 qt = *(const float4*)(B + 512 + t*64 + c*4);
      karr[t] = kt;
      m[t] = red16(DOT4(W, kt));
      p[t] = red16(DOT4(W, qt));
    }
    #pragma unroll
    for (int t = 0; t < 8; ++t){
      vv[t] = B[1024 + t*64 + r];
      sc[t] = *(const float4*)(B + 1536 + t*4);
    }
    float P[56];
    #pragma unroll
    for (int i = 0; i < 14; ++i){
      float4 x = *(const float4*)(B + 1568 + i*4);
      P[i*4] = x.x; P[i*4+1] = x.y; P[i*4+2] = x.z; P[i*4+3] = x.w;
    }
    float d[8], o[8];
    #pragma unroll
    for (int t = 0; t < 8; ++t){
      float a = vv[t] - m[t];
      #pragma unroll
      for (int j = 0; j < t; ++j) a -= P[PIDX(j,t)] * d[j];
      d[t] = sc[t].x * a;
      float oo = p[t];
      #pragma unroll
      for (int j = 0; j < t; ++j) oo += P[28 + PIDX(j,t)] * d[j];
      o[t] = (oo + sc[t].y * d[t]) * sc[t].z;
    }
    #pragma unroll
    for (int t = 0; t < 8; ++t){
      W.x += d[t]*karr[t].x; W.y += d[t]*karr[t].y;
      W.z += d[t]*karr[t].z; W.w += d[t]*karr[t].w;
    }
    if (c < 8){
      float mo = o[0];
      mo = (c==1) ? o[1] : mo;  mo = (c==2) ? o[2] : mo;
      mo = (c==3) ? o[3] : mo;  mo = (c==4) ? o[4] : mo;
      mo = (c==5) ? o[5] : mo;  mo = (c==6) ? o[6] : mo;
      mo = (c==7) ? o[7] : mo;
      lop[(size_t)(T*GQ8 + c)*(BSZ*DMODEL)] = f2bf(mo);
    }
  };

  dma(0, sbuf[0]);
  __builtin_amdgcn_s_waitcnt(0x0F70);   // vmcnt(0)
  for (int T = 0; T < NG8; T += 2){
    dma(T+1, sbuf[1]);                  // async prefetch (overruns into pad at end)
    compute(T, sbuf[0]);
    __builtin_amdgcn_s_waitcnt(0x0F70);
    dma(T+2, sbuf[0]);
    compute(T+1, sbuf[1]);
    __builtin_amdgcn_s_waitcnt(0x0F70);
  }
}

// ------------------------------------------------------------------ residual + layernorm
__global__ __launch_bounds__(256) void ln_kernel(
    const float* __restrict__ hin, const float* __restrict__ attn,
    const float* __restrict__ g, const float* __restrict__ bta,
    float* __restrict__ out){
  int row = blockIdx.x, tid = threadIdx.x;
  size_t rb = (size_t)row * DMODEL;
  float4 hv = ((const float4*)(hin + rb))[tid];
  float4 av = ((const float4*)(attn + rb))[tid];
  float4 x;
  x.x = hv.x + av.x; x.y = hv.y + av.y; x.z = hv.z + av.z; x.w = hv.w + av.w;
  float s  = x.x + x.y + x.z + x.w;
  float ss = x.x*x.x + x.y*x.y + x.z*x.z + x.w*x.w;
  #pragma unroll
  for (int off = 1; off < 64; off <<= 1){
    s  += __shfl_xor(s , off, 64);
    ss += __shfl_xor(ss, off, 64);
  }
  __shared__ float ls[4], lq[4];
  int wv = tid >> 6, ln = tid & 63;
  if (ln == 0){ ls[wv] = s; lq[wv] = ss; }
  __syncthreads();
  s  = ls[0] + ls[1] + ls[2] + ls[3];
  ss = lq[0] + lq[1] + lq[2] + lq[3];
  float mu  = s * (1.f/DMODEL);
  float var = ss * (1.f/DMODEL) - mu*mu;
  float rstd = rsqrtf(var + EPSV);
  float4 gv = ((const float4*)g)[tid], bv = ((const float4*)bta)[tid];
  float4 o;
  o.x = (x.x-mu)*rstd*gv.x + bv.x;
  o.y = (x.y-mu)*rstd*gv.y + bv.y;
  o.z = (x.z-mu)*rstd*gv.z + bv.z;
  o.w = (x.w-mu)*rstd*gv.w + bv.w;
  ((float4*)(out + rb))[tid] = o;
}

// ------------------------------------------------------------------ launch
extern "C" void kernel_launch(void* const* d_in, const int* in_sizes, int n_in,
                              void* d_out, int out_size, void* d_ws, size_t ws_size,
                              hipStream_t stream){
  const float* h     = (const float*)d_in[0];
  const float* wqkvb = (const float*)d_in[1];
  const float* wo    = (const float*)d_in[2];
  const float* lng   = (const float*)d_in[3];
  const float* lnb   = (const float*)d_in[4];
  float* out = (float*)d_out;

  char* w = (char*)d_ws;
  auto take = [&](size_t bytes)->char*{
    char* p = w; w += (bytes + 255) & ~(size_t)255; return p;
  };
  unsigned short* h_bf    = (unsigned short*)take((size_t)MROWS*DMODEL*2);
  unsigned short* wq_bf   = (unsigned short*)take((size_t)NQPAD*DMODEL*2);   // padded rows
  unsigned short* wo_bf   = (unsigned short*)take((size_t)DMODEL*DMODEL*2);
  unsigned short* qkvb_bf = (unsigned short*)take((size_t)MROWS*NQPAD*2);    // padded cols
  float* qb   = (float*)take((size_t)MROWS*DMODEL*4 + 4096);  // +pad for prefetch overrun
  float* kb   = (float*)take((size_t)MROWS*DMODEL*4 + 4096);
  float* vb   = (float*)take((size_t)MROWS*DMODEL*4 + 4096);
  float* Ab   = (float*)take((size_t)MROWS*DMODEL*4);   // reused as attn after kden
  float4* scal = (float4*)take((size_t)64*SLEN*16 + 4096);
  unsigned short* lo_bf = (unsigned short*)take((size_t)MROWS*DMODEL*2);
  float* Sseg = (float*)take((size_t)64*NSEG*64*4);
  float4* pairb = (float4*)take((size_t)64*NG8*16*16 + 8192);
  float* attn = Ab;  // safe alias: Ab consumed by kden before gemm2 writes attn

  cast_bf16_kernel<<<2048, 256, 0, stream>>>(h,     h_bf,  MROWS*DMODEL/4);
  cast_bf16_kernel<<<1024, 256, 0, stream>>>(wqkvb, wq_bf, NQKVB*DMODEL/4);
  cast_bf16_kernel<<<512,  256, 0, stream>>>(wo,    wo_bf, DMODEL*DMODEL/4);

  gemm_big_kernel<true><<<dim3(MROWS/128, NQPAD/128), 256, 0, stream>>>(
      h_bf, wq_bf, qkvb_bf, MROWS, NQPAD, DMODEL);

  prep_kernel<<<MROWS*NHEAD/4, 256, 0, stream>>>(qkvb_bf, qb, kb, vb, scal);
  segsum_kernel<<<dim3(64, NSEG), 64, 0, stream>>>(kb, Sseg);
  scan_kernel<<<dim3(64, NSEG), 64, 0, stream>>>(kb, Sseg, Ab);
  kden_kernel<<<64*SLEN/4, 256, 0, stream>>>(Ab, kb, qb, scal);
  pairdot_kernel<<<64*NG8/4, 256, 0, stream>>>(kb, qb, pairb);
  recur_kernel<<<dim3(64, 16), 64, 0, stream>>>(kb, qb, vb, scal, pairb, lo_bf);

  gemm_big_kernel<false><<<dim3(MROWS/128, DMODEL/128), 256, 0, stream>>>(
      lo_bf, wo_bf, attn, MROWS, DMODEL, DMODEL);

  ln_kernel<<<MROWS, 256, 0, stream>>>(h, attn, lng, lnb, out);
  (void)in_sizes; (void)n_in; (void)out_size; (void)ws_size;
}

// Round 9
// 450.249 us; speedup vs baseline: 1.6360x; 1.6360x over previous
//
#include <hip/hip_runtime.h>
#include <cstdint>
#include <cstddef>

#define D_HEAD   64
#define NHEAD    16
#define DMODEL   1024
#define SLEN     2048
#define BSZ      4
#define MROWS    (SLEN*BSZ)            // 8192
#define NQKVB    (NHEAD*(3*D_HEAD+1))  // 3088
#define NQPAD    3200                  // padded to 25*128 for the 128-tile GEMM
#define EPSV     1e-5f
#define SCALEV   0.125f                // 1/sqrt(64)
#define CHK      64                    // chunk length
#define NCH      (SLEN/CHK)            // 32

typedef short bf16x8 __attribute__((ext_vector_type(8)));
typedef float f32x4  __attribute__((ext_vector_type(4)));

__device__ __forceinline__ unsigned short f2bf(float f){
  unsigned int u = __float_as_uint(f);
  u = (u + 0x7fffu + ((u >> 16) & 1u)) >> 16;   // RNE
  return (unsigned short)u;
}
__device__ __forceinline__ float bf2f(unsigned short s){
  return __uint_as_float(((unsigned int)s) << 16);
}

__device__ __forceinline__ void gload_lds16(const unsigned short* g, unsigned short* l){
  __builtin_amdgcn_global_load_lds((const __attribute__((address_space(1))) void*)g,
                                   (__attribute__((address_space(3))) void*)l, 16, 0, 0);
}

// ------------------------------------------------------------------ cast
__global__ void cast_bf16_kernel(const float* __restrict__ src,
                                 unsigned short* __restrict__ dst, int n4){
  int stride = gridDim.x * blockDim.x;
  for (int i = blockIdx.x*blockDim.x + threadIdx.x; i < n4; i += stride){
    float4 f = ((const float4*)src)[i];
    ushort4 u;
    u.x = f2bf(f.x); u.y = f2bf(f.y); u.z = f2bf(f.z); u.w = f2bf(f.w);
    ((ushort4*)dst)[i] = u;
  }
}

// ------------------------------------------------------------------ GEMM (NT), m97 structure
template<bool OUT_BF16>
__global__ __launch_bounds__(256) void gemm_big_kernel(
    const unsigned short* __restrict__ A, const unsigned short* __restrict__ B,
    void* __restrict__ C, int M, int N, int K){
  __shared__ __align__(16) unsigned short sA[128*32];
  __shared__ __align__(16) unsigned short sB[128*32];
  int m0 = blockIdx.x * 128, n0 = blockIdx.y * 128;
  int tid = threadIdx.x;
  int wv = tid >> 6, ln = tid & 63;
  int lm = ln & 15, quad = ln >> 4;
  int wm = (wv >> 1) * 64, wn = (wv & 1) * 64;
  f32x4 acc[4][4] = {};

  for (int kt = 0; kt < K; kt += 32){
    __syncthreads();
    #pragma unroll
    for (int it = 0; it < 2; ++it){
      int s = wv*128 + it*64 + ln;          // 0..511
      int row = s >> 2, sg = s & 3;
      gload_lds16(A + (size_t)(m0+row)*K + kt + sg*8, sA + (size_t)(wv*128 + it*64)*8);
      gload_lds16(B + (size_t)(n0+row)*K + kt + sg*8, sB + (size_t)(wv*128 + it*64)*8);
    }
    __syncthreads();
    bf16x8 af[4], bfr[4];
    #pragma unroll
    for (int i = 0; i < 4; ++i){
      af[i]  = *(const bf16x8*)(sA + ((wm + i*16 + lm)*32 + quad*8));
      bfr[i] = *(const bf16x8*)(sB + ((wn + i*16 + lm)*32 + quad*8));
    }
    #pragma unroll
    for (int mi = 0; mi < 4; ++mi)
      #pragma unroll
      for (int ni = 0; ni < 4; ++ni)
        acc[mi][ni] = __builtin_amdgcn_mfma_f32_16x16x32_bf16(af[mi], bfr[ni], acc[mi][ni], 0, 0, 0);
  }

  #pragma unroll
  for (int mi = 0; mi < 4; ++mi){
    int rowm = m0 + wm + mi*16 + quad*4;
    #pragma unroll
    for (int ni = 0; ni < 4; ++ni){
      int col = n0 + wn + ni*16 + lm;
      size_t cb = (size_t)rowm * N + col;
      #pragma unroll
      for (int rr = 0; rr < 4; ++rr){
        float v = acc[mi][ni][rr];
        if (OUT_BF16) ((unsigned short*)C)[cb + (size_t)rr*N] = f2bf(v);
        else          ((float*)C)[cb + (size_t)rr*N] = v;
      }
    }
  }
}

// ------------------------------------------------------------------ preprocess
// writes q (fp32 + bf16), k (fp32), v (bf16), sigmoid(beta) into scal.w
__global__ __launch_bounds__(256) void prep_kernel(
    const unsigned short* __restrict__ qkvb,
    float* __restrict__ qb, float* __restrict__ kb,
    unsigned short* __restrict__ qb16, unsigned short* __restrict__ vb16,
    float4* __restrict__ scal){
  int gid = blockIdx.x*4 + (threadIdx.x >> 6);   // m*16 + h
  int ln  = threadIdx.x & 63;
  int m = gid >> 4, h = gid & 15;
  size_t rb = (size_t)m * NQPAD + (size_t)h * 193;
  float qr = bf2f(qkvb[rb + ln]);
  float kr = bf2f(qkvb[rb + 64 + ln]);
  float vr = bf2f(qkvb[rb + 128 + ln]);
  float br = bf2f(qkvb[rb + 192]);
  float q1 = qr > 0.f ? qr + 1.f : __expf(qr);   // elu(x)+1
  float k1 = kr > 0.f ? kr + 1.f : __expf(kr);
  float sq = q1, sk = k1;
  #pragma unroll
  for (int off = 1; off < 64; off <<= 1){
    sq += __shfl_xor(sq, off, 64);
    sk += __shfl_xor(sk, off, 64);
  }
  float qn = q1 / sq, kn = k1 / sk;
  int b = m & 3, t = m >> 2;
  int bh = b*16 + h;
  size_t o = ((size_t)bh*SLEN + t)*64 + ln;
  qb[o] = qn; kb[o] = kn;
  qb16[o] = f2bf(qn);
  vb16[o] = f2bf(vr);
  if (ln == 0){
    float sb = 1.f / (1.f + __expf(-br));
    scal[(size_t)bh*SLEN + t] = make_float4(0.f, 0.f, 0.f, sb);
  }
}

// ------------------------------------------------------------------ segmented cumsum over l
#define NSEG 16
#define SEGL (SLEN/NSEG)   // 128
__global__ __launch_bounds__(64) void segsum_kernel(
    const float* __restrict__ kb, float* __restrict__ S){
  int bh = blockIdx.x, seg = blockIdx.y, ln = threadIdx.x;
  size_t base = ((size_t)bh*SLEN + (size_t)seg*SEGL)*64 + ln;
  float s = 0.f;
  #pragma unroll 4
  for (int t = 0; t < SEGL; ++t) s += kb[base + (size_t)t*64];
  S[((size_t)bh*NSEG + seg)*64 + ln] = s;
}
__global__ __launch_bounds__(64) void scan_kernel(
    const float* __restrict__ kb, const float* __restrict__ S,
    float* __restrict__ Ab){
  int bh = blockIdx.x, seg = blockIdx.y, ln = threadIdx.x;
  float acc = 0.f;
  for (int s = 0; s < seg; ++s) acc += S[((size_t)bh*NSEG + s)*64 + ln];
  size_t base = ((size_t)bh*SLEN + (size_t)seg*SEGL)*64 + ln;
  #pragma unroll 4
  for (int t = 0; t < SEGL; ++t){
    acc += kb[base + (size_t)t*64];
    Ab[base + (size_t)t*64] = acc;
  }
}

// ------------------------------------------------------------------ denominators
// scal = {beta' = beta*kd, <kf,q>, SCALEV/(den+eps), sigmoid(beta)}; kb <- kf; kb16 <- bf16(kf)
__global__ __launch_bounds__(256) void kden_kernel(
    const float* __restrict__ Ab, float* __restrict__ kb,
    const float* __restrict__ qb, unsigned short* __restrict__ kb16,
    float4* __restrict__ scal){
  int gid = blockIdx.x*4 + (threadIdx.x >> 6);   // bh*2048 + t
  int ln  = threadIdx.x & 63;
  int t = gid & (SLEN-1);
  size_t o = (size_t)gid*64 + ln;
  float a = Ab[o], kn = kb[o], qn = qb[o];
  float d0 = (a - kn)*kn, d1 = a*qn, d2 = kn*qn;
  #pragma unroll
  for (int off = 1; off < 64; off <<= 1){
    d0 += __shfl_xor(d0, off, 64);
    d1 += __shfl_xor(d1, off, 64);
    d2 += __shfl_xor(d2, off, 64);
  }
  float kd  = (t == 0) ? 1.f : d0;
  float inv = 1.f / (kd + EPSV);
  float kf = kn * inv;
  kb[o] = kf;
  kb16[o] = f2bf(kf);
  if (ln == 0){
    float4 s = scal[gid];
    scal[gid] = make_float4(s.w * kd, d2 * inv, SCALEV/(d1 + EPSV), 0.f);
  }
}

// ------------------------------------------------------------------ precompute per (bh,chunk):
// Akk = K K^T (fp32, LDS), Bq = tril(Q K^T) incl diag (bf16 -> global),
// Dmat = (I + diag(b')*strictlow(Akk))^-1 diag(b')  (bf16 -> global).
__global__ __launch_bounds__(64, 1) void precomp_kernel(
    const unsigned short* __restrict__ K16, const unsigned short* __restrict__ Q16,
    const float4* __restrict__ scal,
    unsigned short* __restrict__ Dg, unsigned short* __restrict__ Bg){
  __shared__ __align__(16) float sA[64*64];
  __shared__ float sbp[64];
  int inst = blockIdx.x;
  int bh = inst >> 5, ch = inst & 31;
  int ln = threadIdx.x, lm = ln & 15, quad = ln >> 4;
  const unsigned short* Kg = K16 + ((size_t)bh*SLEN + ch*CHK)*64;
  const unsigned short* Qg = Q16 + ((size_t)bh*SLEN + ch*CHK)*64;

  // Akk GEMM
  {
    f32x4 acc[4][4] = {};
    #pragma unroll
    for (int s = 0; s < 2; ++s){
      bf16x8 kf[4];
      #pragma unroll
      for (int i = 0; i < 4; ++i)
        kf[i] = *(const bf16x8*)(Kg + (size_t)(i*16+lm)*64 + s*32 + quad*8);
      #pragma unroll
      for (int mi = 0; mi < 4; ++mi)
        #pragma unroll
        for (int ni = 0; ni < 4; ++ni)
          acc[mi][ni] = __builtin_amdgcn_mfma_f32_16x16x32_bf16(kf[mi], kf[ni], acc[mi][ni], 0, 0, 0);
    }
    #pragma unroll
    for (int mi = 0; mi < 4; ++mi)
      #pragma unroll
      for (int ni = 0; ni < 4; ++ni)
        #pragma unroll
        for (int rr = 0; rr < 4; ++rr)
          sA[(mi*16+quad*4+rr)*64 + ni*16+lm] = acc[mi][ni][rr];
  }
  sbp[ln] = scal[(size_t)bh*SLEN + ch*CHK + ln].x;
  __syncthreads();

  // Bq GEMM, masked store
  {
    f32x4 acc[4][4] = {};
    #pragma unroll
    for (int s = 0; s < 2; ++s){
      bf16x8 kf[4], qf[4];
      #pragma unroll
      for (int i = 0; i < 4; ++i){
        kf[i] = *(const bf16x8*)(Kg + (size_t)(i*16+lm)*64 + s*32 + quad*8);
        qf[i] = *(const bf16x8*)(Qg + (size_t)(i*16+lm)*64 + s*32 + quad*8);
      }
      #pragma unroll
      for (int mi = 0; mi < 4; ++mi)
        #pragma unroll
        for (int ni = 0; ni < 4; ++ni)
          acc[mi][ni] = __builtin_amdgcn_mfma_f32_16x16x32_bf16(qf[mi], kf[ni], acc[mi][ni], 0, 0, 0);
    }
    size_t io = (size_t)inst*4096;
    #pragma unroll
    for (int mi = 0; mi < 4; ++mi)
      #pragma unroll
      for (int ni = 0; ni < 4; ++ni)
        #pragma unroll
        for (int rr = 0; rr < 4; ++rr){
          int t = mi*16+quad*4+rr, j = ni*16+lm;
          float v = (j <= t) ? acc[mi][ni][rr] : 0.f;
          Bg[io + (size_t)t*64 + j] = f2bf(v);
        }
  }

  // triangular inversion: X = (I + diag(b')L)^-1 diag(b'); lane = column j
  {
    float x[64];
    x[0] = (ln == 0) ? sbp[0] : 0.f;
    #pragma unroll
    for (int i = 1; i < 64; ++i){
      float bi = sbp[i];
      float s = 0.f;
      #pragma unroll
      for (int m4 = 0; m4*4 < i; ++m4){
        float4 a = *(const float4*)&sA[i*64 + m4*4];
        if (m4*4+0 < i) s += a.x * x[m4*4+0];
        if (m4*4+1 < i) s += a.y * x[m4*4+1];
        if (m4*4+2 < i) s += a.z * x[m4*4+2];
        if (m4*4+3 < i) s += a.w * x[m4*4+3];
      }
      x[i] = ((ln == i) ? bi : 0.f) - bi*s;
    }
    size_t io = (size_t)inst*4096;
    #pragma unroll
    for (int i = 0; i < 64; ++i)
      Dg[io + (size_t)i*64 + ln] = f2bf(x[i]);
  }
}

// ------------------------------------------------------------------ chunked delta-rule, MFMA
// one workgroup (4 waves) per bh; 32 sequential chunks. W kept in fp32 C-frags.
__global__ __launch_bounds__(256, 1) void chunk_kernel(
    const unsigned short* __restrict__ K16, const unsigned short* __restrict__ Q16,
    const unsigned short* __restrict__ V16,
    const unsigned short* __restrict__ Dg, const unsigned short* __restrict__ Bg,
    const float4* __restrict__ scal, unsigned short* __restrict__ lo){
  __shared__ __align__(16) unsigned short sK[4096];   // K rows, then K^T (swizzled) in-place
  __shared__ __align__(16) unsigned short sQ[4096];   // Q rows, then X^T (swizzled)
  __shared__ __align__(16) unsigned short sV[4096];
  __shared__ __align__(16) unsigned short sD[4096];
  __shared__ __align__(16) unsigned short sB[4096];
  __shared__ __align__(16) unsigned short sW[4096];   // W rows (r, d) bf16
  __shared__ __align__(16) unsigned short sDT[4096];  // Delta^T rows (r, t) bf16
  int bh = blockIdx.x;
  int tid = threadIdx.x, wv = tid >> 6, ln = tid & 63, lm = ln & 15, quad = ln >> 4;
  size_t sb = (size_t)bh*SLEN*64;
  const unsigned short* Kg = K16 + sb;
  const unsigned short* Qg = Q16 + sb;
  const unsigned short* Vg = V16 + sb;
  const float4* scp = scal + (size_t)bh*SLEN;
  size_t lobase = (size_t)(bh>>4)*DMODEL + (size_t)(bh&15)*64;

  auto dma_arr = [&](const unsigned short* g, unsigned short* s){
    #pragma unroll
    for (int it = 0; it < 2; ++it){
      int seg = wv*2 + it;
      gload_lds16(g + seg*512 + ln*8, s + seg*512);
    }
  };
  auto dma_chunk = [&](int ch){
    size_t co = (size_t)ch*CHK*64;
    dma_arr(Kg + co, sK);
    dma_arr(Qg + co, sQ);
    dma_arr(Vg + co, sV);
    size_t io = ((size_t)bh*NCH + ch)*4096;
    dma_arr(Dg + io, sD);
    dma_arr(Bg + io, sB);
  };
  // generic 64x64x64 GEMM: wave strip rows [wv*16, wv*16+16)
  auto gemm = [&](const unsigned short* A, bool swzA, const unsigned short* B, bool swzB,
                  f32x4* acc){
    #pragma unroll
    for (int s = 0; s < 2; ++s){
      int ak = s*32 + quad*8;
      int ar = wv*16 + lm;
      bf16x8 af = *(const bf16x8*)(A + ar*64 + (swzA ? (ak ^ ((ar&7)<<3)) : ak));
      #pragma unroll
      for (int n = 0; n < 4; ++n){
        int br = n*16 + lm;
        bf16x8 bf = *(const bf16x8*)(B + br*64 + (swzB ? (ak ^ ((br&7)<<3)) : ak));
        acc[n] = __builtin_amdgcn_mfma_f32_16x16x32_bf16(af, bf, acc[n], 0, 0, 0);
      }
    }
  };

  // init: zero W LDS, persistent W accumulator frags
  uint4 z = make_uint4(0,0,0,0);
  ((uint4*)sW)[tid] = z;  ((uint4*)sW)[tid + 256] = z;
  f32x4 Wacc[4] = {};
  dma_chunk(0);

  for (int ch = 0; ch < NCH; ++ch){
    // per-row output scale for this chunk (4 rows per lane)
    int tbase = ch*CHK + wv*16 + quad*4;
    float scz0 = scp[tbase+0].z, scz1 = scp[tbase+1].z,
          scz2 = scp[tbase+2].z, scz3 = scp[tbase+3].z;
    __builtin_amdgcn_s_waitcnt(0x0F70);   // vmcnt(0): DMA + scz landed
    __syncthreads();

    // M = K W0^T, Mq = Q W0^T  (strips over t)
    f32x4 Macc[4] = {}, Mqacc[4] = {};
    gemm(sK, false, sW, false, Macc);
    gemm(sQ, false, sW, false, Mqacc);
    __syncthreads();                      // all reads of sK/sQ rows done

    // phase1: read K into regs for transpose; write X^T (over sQ, swizzled)
    unsigned short kreg[16];
    *(uint4*)&kreg[0] = ((const uint4*)sK)[tid*2];
    *(uint4*)&kreg[8] = ((const uint4*)sK)[tid*2 + 1];
    #pragma unroll
    for (int n = 0; n < 4; ++n)
      #pragma unroll
      for (int rr = 0; rr < 4; ++rr){
        int t = wv*16 + quad*4 + rr;      // within chunk
        int r = n*16 + lm;
        float x = bf2f(sV[t*64 + r]) - Macc[n][rr];
        sQ[r*64 + ((t & 56) ^ ((r&7)<<3)) + (t & 7)] = f2bf(x);
      }
    __syncthreads();
    // phase2: write K^T (over sK, swizzled)
    {
      int t = tid >> 2, d0 = (tid & 3)*16;
      #pragma unroll
      for (int e = 0; e < 16; ++e){
        int d = d0 + e;
        sK[d*64 + ((t & 56) ^ ((d&7)<<3)) + (t & 7)] = kreg[e];
      }
    }
    __syncthreads();

    // Delta^T = X^T D^T : strips over r; A = X^T (swz), B = D rows t
    f32x4 Dacc[4] = {};
    gemm(sQ, true, sD, false, Dacc);
    #pragma unroll
    for (int n = 0; n < 4; ++n)
      #pragma unroll
      for (int rr = 0; rr < 4; ++rr)
        sDT[(wv*16+quad*4+rr)*64 + n*16+lm] = f2bf(Dacc[n][rr]);
    __syncthreads();

    // O = Mq + Bq_masked * Delta : strips over t; store scaled bf16 to lo
    f32x4 Oacc[4] = { Mqacc[0], Mqacc[1], Mqacc[2], Mqacc[3] };
    gemm(sB, false, sDT, false, Oacc);
    #pragma unroll
    for (int n = 0; n < 4; ++n)
      #pragma unroll
      for (int rr = 0; rr < 4; ++rr){
        int tabs = ch*CHK + wv*16 + quad*4 + rr;
        int r = n*16 + lm;
        float scz = (rr==0)?scz0:(rr==1)?scz1:(rr==2)?scz2:scz3;
        lo[lobase + (size_t)tabs*(BSZ*DMODEL) + r] = f2bf(Oacc[n][rr] * scz);
      }

    // W += Delta^T K : strips over r; A = Delta^T rows r, B = K^T (swz) rows d
    gemm(sDT, false, sK, true, Wacc);
    __syncthreads();                      // all LDS reads of this chunk done

    if (ch + 1 < NCH) dma_chunk(ch + 1);  // async into freed regions
    // spill W (fp32 frags -> bf16 rows) for next chunk's M/Mq
    #pragma unroll
    for (int n = 0; n < 4; ++n)
      #pragma unroll
      for (int rr = 0; rr < 4; ++rr)
        sW[(wv*16+quad*4+rr)*64 + n*16+lm] = f2bf(Wacc[n][rr]);
    // next iteration: waitcnt + barrier covers both DMA and sW writes
  }
}

// ------------------------------------------------------------------ residual + layernorm
__global__ __launch_bounds__(256) void ln_kernel(
    const float* __restrict__ hin, const float* __restrict__ attn,
    const float* __restrict__ g, const float* __restrict__ bta,
    float* __restrict__ out){
  int row = blockIdx.x, tid = threadIdx.x;
  size_t rb = (size_t)row * DMODEL;
  float4 hv = ((const float4*)(hin + rb))[tid];
  float4 av = ((const float4*)(attn + rb))[tid];
  float4 x;
  x.x = hv.x + av.x; x.y = hv.y + av.y; x.z = hv.z + av.z; x.w = hv.w + av.w;
  float s  = x.x + x.y + x.z + x.w;
  float ss = x.x*x.x + x.y*x.y + x.z*x.z + x.w*x.w;
  #pragma unroll
  for (int off = 1; off < 64; off <<= 1){
    s  += __shfl_xor(s , off, 64);
    ss += __shfl_xor(ss, off, 64);
  }
  __shared__ float ls[4], lq[4];
  int wv = tid >> 6, ln = tid & 63;
  if (ln == 0){ ls[wv] = s; lq[wv] = ss; }
  __syncthreads();
  s  = ls[0] + ls[1] + ls[2] + ls[3];
  ss = lq[0] + lq[1] + lq[2] + lq[3];
  float mu  = s * (1.f/DMODEL);
  float var = ss * (1.f/DMODEL) - mu*mu;
  float rstd = rsqrtf(var + EPSV);
  float4 gv = ((const float4*)g)[tid], bv = ((const float4*)bta)[tid];
  float4 o;
  o.x = (x.x-mu)*rstd*gv.x + bv.x;
  o.y = (x.y-mu)*rstd*gv.y + bv.y;
  o.z = (x.z-mu)*rstd*gv.z + bv.z;
  o.w = (x.w-mu)*rstd*gv.w + bv.w;
  ((float4*)(out + rb))[tid] = o;
}

// ------------------------------------------------------------------ launch
extern "C" void kernel_launch(void* const* d_in, const int* in_sizes, int n_in,
                              void* d_out, int out_size, void* d_ws, size_t ws_size,
                              hipStream_t stream){
  const float* h     = (const float*)d_in[0];
  const float* wqkvb = (const float*)d_in[1];
  const float* wo    = (const float*)d_in[2];
  const float* lng   = (const float*)d_in[3];
  const float* lnb   = (const float*)d_in[4];
  float* out = (float*)d_out;

  char* w = (char*)d_ws;
  auto take = [&](size_t bytes)->char*{
    char* p = w; w += (bytes + 255) & ~(size_t)255; return p;
  };
  unsigned short* h_bf    = (unsigned short*)take((size_t)MROWS*DMODEL*2);
  unsigned short* wq_bf   = (unsigned short*)take((size_t)NQPAD*DMODEL*2);
  unsigned short* wo_bf   = (unsigned short*)take((size_t)DMODEL*DMODEL*2);
  unsigned short* qkvb_bf = (unsigned short*)take((size_t)MROWS*NQPAD*2);
  float* qb   = (float*)take((size_t)MROWS*DMODEL*4 + 4096);
  float* kb   = (float*)take((size_t)MROWS*DMODEL*4 + 4096);
  float* Ab   = (float*)take((size_t)MROWS*DMODEL*4);   // aliased: D+Bq after kden; attn after chunk
  float4* scal = (float4*)take((size_t)64*SLEN*16 + 4096);
  unsigned short* lo_bf = (unsigned short*)take((size_t)MROWS*DMODEL*2);
  float* Sseg = (float*)take((size_t)64*NSEG*64*4);
  unsigned short* kb16 = (unsigned short*)take((size_t)MROWS*DMODEL*2);
  unsigned short* qb16 = (unsigned short*)take((size_t)MROWS*DMODEL*2);
  unsigned short* vb16 = (unsigned short*)take((size_t)MROWS*DMODEL*2);
  // aliases over Ab (32MB): Dg 16MB + Bg 16MB; attn reuses the same 32MB later
  unsigned short* Dg = (unsigned short*)Ab;
  unsigned short* Bg = (unsigned short*)Ab + (size_t)64*NCH*4096;
  float* attn = Ab;

  cast_bf16_kernel<<<2048, 256, 0, stream>>>(h,     h_bf,  MROWS*DMODEL/4);
  cast_bf16_kernel<<<1024, 256, 0, stream>>>(wqkvb, wq_bf, NQKVB*DMODEL/4);
  cast_bf16_kernel<<<512,  256, 0, stream>>>(wo,    wo_bf, DMODEL*DMODEL/4);

  gemm_big_kernel<true><<<dim3(MROWS/128, NQPAD/128), 256, 0, stream>>>(
      h_bf, wq_bf, qkvb_bf, MROWS, NQPAD, DMODEL);

  prep_kernel<<<MROWS*NHEAD/4, 256, 0, stream>>>(qkvb_bf, qb, kb, qb16, vb16, scal);
  segsum_kernel<<<dim3(64, NSEG), 64, 0, stream>>>(kb, Sseg);
  scan_kernel<<<dim3(64, NSEG), 64, 0, stream>>>(kb, Sseg, Ab);
  kden_kernel<<<64*SLEN/4, 256, 0, stream>>>(Ab, kb, qb, kb16, scal);
  precomp_kernel<<<64*NCH, 64, 0, stream>>>(kb16, qb16, scal, Dg, Bg);
  chunk_kernel<<<64, 256, 0, stream>>>(kb16, qb16, vb16, Dg, Bg, scal, lo_bf);

  gemm_big_kernel<false><<<dim3(MROWS/128, DMODEL/128), 256, 0, stream>>>(
      lo_bf, wo_bf, attn, MROWS, DMODEL, DMODEL);

  ln_kernel<<<MROWS, 256, 0, stream>>>(h, attn, lng, lnb, out);
  (void)in_sizes; (void)n_in; (void)out_size; (void)ws_size;
}

// Round 10
// 402.143 us; speedup vs baseline: 1.8317x; 1.1196x over previous
//
#include <hip/hip_runtime.h>
#include <cstdint>
#include <cstddef>

#define D_HEAD   64
#define NHEAD    16
#define DMODEL   1024
#define SLEN     2048
#define BSZ      4
#define MROWS    (SLEN*BSZ)            // 8192
#define NQKVB    (NHEAD*(3*D_HEAD+1))  // 3088
#define NQPAD    3200                  // padded to 25*128 for the 128-tile GEMM
#define EPSV     1e-5f
#define SCALEV   0.125f                // 1/sqrt(64)
#define CHK      64                    // chunk length
#define NCH      (SLEN/CHK)            // 32

typedef short bf16x8 __attribute__((ext_vector_type(8)));
typedef float f32x4  __attribute__((ext_vector_type(4)));

__device__ __forceinline__ unsigned short f2bf(float f){
  unsigned int u = __float_as_uint(f);
  u = (u + 0x7fffu + ((u >> 16) & 1u)) >> 16;   // RNE
  return (unsigned short)u;
}
__device__ __forceinline__ float bf2f(unsigned short s){
  return __uint_as_float(((unsigned int)s) << 16);
}

__device__ __forceinline__ void gload_lds16(const unsigned short* g, unsigned short* l){
  __builtin_amdgcn_global_load_lds((const __attribute__((address_space(1))) void*)g,
                                   (__attribute__((address_space(3))) void*)l, 16, 0, 0);
}

// swizzled in-row offset: XOR the 8-element block index with (row&7)
#define SWZ(row, col) ((col) ^ (((row)&7)<<3))

// ------------------------------------------------------------------ cast
__global__ void cast_bf16_kernel(const float* __restrict__ src,
                                 unsigned short* __restrict__ dst, int n4){
  int stride = gridDim.x * blockDim.x;
  for (int i = blockIdx.x*blockDim.x + threadIdx.x; i < n4; i += stride){
    float4 f = ((const float4*)src)[i];
    ushort4 u;
    u.x = f2bf(f.x); u.y = f2bf(f.y); u.z = f2bf(f.z); u.w = f2bf(f.w);
    ((ushort4*)dst)[i] = u;
  }
}

// ------------------------------------------------------------------ GEMM (NT), m97 structure
template<bool OUT_BF16>
__global__ __launch_bounds__(256) void gemm_big_kernel(
    const unsigned short* __restrict__ A, const unsigned short* __restrict__ B,
    void* __restrict__ C, int M, int N, int K){
  __shared__ __align__(16) unsigned short sA[128*32];
  __shared__ __align__(16) unsigned short sB[128*32];
  int m0 = blockIdx.x * 128, n0 = blockIdx.y * 128;
  int tid = threadIdx.x;
  int wv = tid >> 6, ln = tid & 63;
  int lm = ln & 15, quad = ln >> 4;
  int wm = (wv >> 1) * 64, wn = (wv & 1) * 64;
  f32x4 acc[4][4] = {};

  for (int kt = 0; kt < K; kt += 32){
    __syncthreads();
    #pragma unroll
    for (int it = 0; it < 2; ++it){
      int s = wv*128 + it*64 + ln;          // 0..511
      int row = s >> 2, sg = s & 3;
      gload_lds16(A + (size_t)(m0+row)*K + kt + sg*8, sA + (size_t)(wv*128 + it*64)*8);
      gload_lds16(B + (size_t)(n0+row)*K + kt + sg*8, sB + (size_t)(wv*128 + it*64)*8);
    }
    __syncthreads();
    bf16x8 af[4], bfr[4];
    #pragma unroll
    for (int i = 0; i < 4; ++i){
      af[i]  = *(const bf16x8*)(sA + ((wm + i*16 + lm)*32 + quad*8));
      bfr[i] = *(const bf16x8*)(sB + ((wn + i*16 + lm)*32 + quad*8));
    }
    #pragma unroll
    for (int mi = 0; mi < 4; ++mi)
      #pragma unroll
      for (int ni = 0; ni < 4; ++ni)
        acc[mi][ni] = __builtin_amdgcn_mfma_f32_16x16x32_bf16(af[mi], bfr[ni], acc[mi][ni], 0, 0, 0);
  }

  #pragma unroll
  for (int mi = 0; mi < 4; ++mi){
    int rowm = m0 + wm + mi*16 + quad*4;
    #pragma unroll
    for (int ni = 0; ni < 4; ++ni){
      int col = n0 + wn + ni*16 + lm;
      size_t cb = (size_t)rowm * N + col;
      #pragma unroll
      for (int rr = 0; rr < 4; ++rr){
        float v = acc[mi][ni][rr];
        if (OUT_BF16) ((unsigned short*)C)[cb + (size_t)rr*N] = f2bf(v);
        else          ((float*)C)[cb + (size_t)rr*N] = v;
      }
    }
  }
}

// ------------------------------------------------------------------ preprocess
// q: fp32 + bf16(SWIZZLED per 64-chunk row), k: fp32, v: bf16 (linear)
__global__ __launch_bounds__(256) void prep_kernel(
    const unsigned short* __restrict__ qkvb,
    float* __restrict__ qb, float* __restrict__ kb,
    unsigned short* __restrict__ qb16, unsigned short* __restrict__ vb16,
    float4* __restrict__ scal){
  int gid = blockIdx.x*4 + (threadIdx.x >> 6);   // m*16 + h
  int ln  = threadIdx.x & 63;
  int m = gid >> 4, h = gid & 15;
  size_t rb = (size_t)m * NQPAD + (size_t)h * 193;
  float qr = bf2f(qkvb[rb + ln]);
  float kr = bf2f(qkvb[rb + 64 + ln]);
  float vr = bf2f(qkvb[rb + 128 + ln]);
  float br = bf2f(qkvb[rb + 192]);
  float q1 = qr > 0.f ? qr + 1.f : __expf(qr);   // elu(x)+1
  float k1 = kr > 0.f ? kr + 1.f : __expf(kr);
  float sq = q1, sk = k1;
  #pragma unroll
  for (int off = 1; off < 64; off <<= 1){
    sq += __shfl_xor(sq, off, 64);
    sk += __shfl_xor(sk, off, 64);
  }
  float qn = q1 / sq, kn = k1 / sk;
  int b = m & 3, t = m >> 2;
  int bh = b*16 + h;
  size_t row = ((size_t)bh*SLEN + t)*64;
  qb[row + ln] = qn; kb[row + ln] = kn;
  qb16[row + SWZ(t, ln)] = f2bf(qn);
  vb16[row + ln] = f2bf(vr);
  if (ln == 0){
    float sb = 1.f / (1.f + __expf(-br));
    scal[(size_t)bh*SLEN + t] = make_float4(0.f, 0.f, 0.f, sb);
  }
}

// ------------------------------------------------------------------ segmented cumsum over l
#define NSEG 16
#define SEGL (SLEN/NSEG)   // 128
__global__ __launch_bounds__(64) void segsum_kernel(
    const float* __restrict__ kb, float* __restrict__ S){
  int bh = blockIdx.x, seg = blockIdx.y, ln = threadIdx.x;
  size_t base = ((size_t)bh*SLEN + (size_t)seg*SEGL)*64 + ln;
  float s = 0.f;
  #pragma unroll 4
  for (int t = 0; t < SEGL; ++t) s += kb[base + (size_t)t*64];
  S[((size_t)bh*NSEG + seg)*64 + ln] = s;
}
__global__ __launch_bounds__(64) void scan_kernel(
    const float* __restrict__ kb, const float* __restrict__ S,
    float* __restrict__ Ab){
  int bh = blockIdx.x, seg = blockIdx.y, ln = threadIdx.x;
  float acc = 0.f;
  for (int s = 0; s < seg; ++s) acc += S[((size_t)bh*NSEG + s)*64 + ln];
  size_t base = ((size_t)bh*SLEN + (size_t)seg*SEGL)*64 + ln;
  #pragma unroll 4
  for (int t = 0; t < SEGL; ++t){
    acc += kb[base + (size_t)t*64];
    Ab[base + (size_t)t*64] = acc;
  }
}

// ------------------------------------------------------------------ denominators
// scal = {beta*kd, <kf,q>, SCALEV/(den+eps), sigmoid(beta)}; kb16 <- bf16(kf) SWIZZLED
__global__ __launch_bounds__(256) void kden_kernel(
    const float* __restrict__ Ab, float* __restrict__ kb,
    const float* __restrict__ qb, unsigned short* __restrict__ kb16,
    float4* __restrict__ scal){
  int gid = blockIdx.x*4 + (threadIdx.x >> 6);   // bh*2048 + t
  int ln  = threadIdx.x & 63;
  int t = gid & (SLEN-1);
  size_t o = (size_t)gid*64 + ln;
  float a = Ab[o], kn = kb[o], qn = qb[o];
  float d0 = (a - kn)*kn, d1 = a*qn, d2 = kn*qn;
  #pragma unroll
  for (int off = 1; off < 64; off <<= 1){
    d0 += __shfl_xor(d0, off, 64);
    d1 += __shfl_xor(d1, off, 64);
    d2 += __shfl_xor(d2, off, 64);
  }
  float kd  = (t == 0) ? 1.f : d0;
  float inv = 1.f / (kd + EPSV);
  float kf = kn * inv;
  kb[o] = kf;
  kb16[(size_t)gid*64 + SWZ(t, ln)] = f2bf(kf);
  if (ln == 0){
    float4 s = scal[gid];
    scal[gid] = make_float4(s.w * kd, d2 * inv, SCALEV/(d1 + EPSV), 0.f);
  }
}

// ------------------------------------------------------------------ precompute per (bh,chunk):
// Akk = K K^T (fp32, LDS), Bq = tril(Q K^T) incl diag (bf16 -> global, SWIZZLED),
// Dmat = (I + diag(b')*strictlow(Akk))^-1 diag(b')  (bf16 -> global, SWIZZLED).
// Kg/Qg are swizzled in global; fragment reads apply the same swizzle.
__global__ __launch_bounds__(64, 1) void precomp_kernel(
    const unsigned short* __restrict__ K16, const unsigned short* __restrict__ Q16,
    const float4* __restrict__ scal,
    unsigned short* __restrict__ Dg, unsigned short* __restrict__ Bg){
  __shared__ __align__(16) float sA[64*64];
  __shared__ float sbp[64];
  int inst = blockIdx.x;
  int bh = inst >> 5, ch = inst & 31;
  int ln = threadIdx.x, lm = ln & 15, quad = ln >> 4;
  const unsigned short* Kg = K16 + ((size_t)bh*SLEN + ch*CHK)*64;
  const unsigned short* Qg = Q16 + ((size_t)bh*SLEN + ch*CHK)*64;

  // Akk GEMM
  {
    f32x4 acc[4][4] = {};
    #pragma unroll
    for (int s = 0; s < 2; ++s){
      bf16x8 kf[4];
      #pragma unroll
      for (int i = 0; i < 4; ++i){
        int row = i*16+lm;
        kf[i] = *(const bf16x8*)(Kg + (size_t)row*64 + SWZ(row, s*32 + quad*8));
      }
      #pragma unroll
      for (int mi = 0; mi < 4; ++mi)
        #pragma unroll
        for (int ni = 0; ni < 4; ++ni)
          acc[mi][ni] = __builtin_amdgcn_mfma_f32_16x16x32_bf16(kf[mi], kf[ni], acc[mi][ni], 0, 0, 0);
    }
    #pragma unroll
    for (int mi = 0; mi < 4; ++mi)
      #pragma unroll
      for (int ni = 0; ni < 4; ++ni)
        #pragma unroll
        for (int rr = 0; rr < 4; ++rr)
          sA[(mi*16+quad*4+rr)*64 + ni*16+lm] = acc[mi][ni][rr];
  }
  sbp[ln] = scal[(size_t)bh*SLEN + ch*CHK + ln].x;
  __syncthreads();

  // Bq GEMM, masked swizzled store
  {
    f32x4 acc[4][4] = {};
    #pragma unroll
    for (int s = 0; s < 2; ++s){
      bf16x8 kf[4], qf[4];
      #pragma unroll
      for (int i = 0; i < 4; ++i){
        int row = i*16+lm;
        kf[i] = *(const bf16x8*)(Kg + (size_t)row*64 + SWZ(row, s*32 + quad*8));
        qf[i] = *(const bf16x8*)(Qg + (size_t)row*64 + SWZ(row, s*32 + quad*8));
      }
      #pragma unroll
      for (int mi = 0; mi < 4; ++mi)
        #pragma unroll
        for (int ni = 0; ni < 4; ++ni)
          acc[mi][ni] = __builtin_amdgcn_mfma_f32_16x16x32_bf16(qf[mi], kf[ni], acc[mi][ni], 0, 0, 0);
    }
    size_t io = (size_t)inst*4096;
    #pragma unroll
    for (int mi = 0; mi < 4; ++mi)
      #pragma unroll
      for (int ni = 0; ni < 4; ++ni)
        #pragma unroll
        for (int rr = 0; rr < 4; ++rr){
          int t = mi*16+quad*4+rr, j = ni*16+lm;
          float v = (j <= t) ? acc[mi][ni][rr] : 0.f;
          Bg[io + (size_t)t*64 + SWZ(t, j)] = f2bf(v);
        }
  }

  // triangular inversion: X = (I + diag(b')L)^-1 diag(b'); lane = column j
  {
    float x[64];
    x[0] = (ln == 0) ? sbp[0] : 0.f;
    #pragma unroll
    for (int i = 1; i < 64; ++i){
      float bi = sbp[i];
      float s = 0.f;
      #pragma unroll
      for (int m4 = 0; m4*4 < i; ++m4){
        float4 a = *(const float4*)&sA[i*64 + m4*4];
        if (m4*4+0 < i) s += a.x * x[m4*4+0];
        if (m4*4+1 < i) s += a.y * x[m4*4+1];
        if (m4*4+2 < i) s += a.z * x[m4*4+2];
        if (m4*4+3 < i) s += a.w * x[m4*4+3];
      }
      x[i] = ((ln == i) ? bi : 0.f) - bi*s;
    }
    size_t io = (size_t)inst*4096;
    #pragma unroll
    for (int i = 0; i < 64; ++i)
      Dg[io + (size_t)i*64 + SWZ(i, ln)] = f2bf(x[i]);
  }
}

// ------------------------------------------------------------------ chunked delta-rule, MFMA, r-split
// grid (64 bh, 4 rgroup); each block owns W rows r = rg*16..rg*16+15.
// All LDS bf16 tiles XOR-swizzled; K/Q/D/B pre-swizzled in global, DMA'd linear.
__global__ __launch_bounds__(256, 1) void chunk_kernel(
    const unsigned short* __restrict__ K16, const unsigned short* __restrict__ Q16,
    const unsigned short* __restrict__ V16,
    const unsigned short* __restrict__ Dg, const unsigned short* __restrict__ Bg,
    const float4* __restrict__ scal, unsigned short* __restrict__ lo){
  __shared__ __align__(16) unsigned short sK[4096];   // K (t,d) swz
  __shared__ __align__(16) unsigned short sQ[4096];   // Q (t,d) swz
  __shared__ __align__(16) unsigned short sD[4096];   // D (t,j) swz
  __shared__ __align__(16) unsigned short sB[4096];   // Bq (t,j) swz
  __shared__ __align__(16) unsigned short sKT[4096];  // K^T (d,t) swz
  __shared__ __align__(16) unsigned short sV[1024];   // V strip (t, 16r) linear
  __shared__ __align__(16) unsigned short sX[1024];   // X^T (16r, t) swz
  __shared__ __align__(16) unsigned short sDT[1024];  // Delta^T (16r, t) swz
  __shared__ __align__(16) unsigned short sW[1024];   // W strip (16r, d) swz
  int bh = blockIdx.x, rg = blockIdx.y;
  int tid = threadIdx.x, wv = tid >> 6, ln = tid & 63, lm = ln & 15, quad = ln >> 4;
  size_t sb = (size_t)bh*SLEN*64;
  const unsigned short* Kg = K16 + sb;
  const unsigned short* Qg = Q16 + sb;
  const unsigned short* Vg = V16 + sb;
  const float4* scp = scal + (size_t)bh*SLEN;
  size_t lobase = (size_t)(bh>>4)*DMODEL + (size_t)(bh&15)*64 + rg*16;

  auto dma8 = [&](const unsigned short* g, unsigned short* s){
    #pragma unroll
    for (int it = 0; it < 2; ++it)
      gload_lds16(g + (wv*2+it)*512 + ln*8, s + (wv*2+it)*512);
  };
  auto dma_chunk = [&](int ch){
    size_t co = (size_t)ch*CHK*64;
    dma8(Kg + co, sK);
    dma8(Qg + co, sQ);
    size_t io = ((size_t)bh*NCH + ch)*4096;
    dma8(Dg + io, sD);
    dma8(Bg + io, sB);
    if (wv == 0){
      gload_lds16(Vg + co + (size_t)(ln>>1)*64 + rg*16 + (ln&1)*8, sV);
      gload_lds16(Vg + co + (size_t)(32 + (ln>>1))*64 + rg*16 + (ln&1)*8, sV + 512);
    }
  };
  auto frag = [&](const unsigned short* S, int row, int kb)->bf16x8 {
    return *(const bf16x8*)(S + row*64 + SWZ(row, kb));
  };

  if (tid < 128) ((uint4*)sW)[tid] = make_uint4(0u,0u,0u,0u);
  f32x4 Wacc = {0,0,0,0};
  dma_chunk(0);

  for (int ch = 0; ch < NCH; ++ch){
    int tb = ch*CHK + wv*16 + quad*4;
    float sz0 = scp[tb+0].z, sz1 = scp[tb+1].z, sz2 = scp[tb+2].z, sz3 = scp[tb+3].z;
    __builtin_amdgcn_s_waitcnt(0x0F70);   // vmcnt(0)
    __syncthreads();

    // phase0: M = K W^T, Mq = Q W^T (wave = t-tile wv)
    f32x4 Macc = {0,0,0,0}, Mqacc = {0,0,0,0};
    #pragma unroll
    for (int s = 0; s < 2; ++s){
      int kb = s*32 + quad*8;
      bf16x8 ak = frag(sK, wv*16+lm, kb);
      bf16x8 aq = frag(sQ, wv*16+lm, kb);
      bf16x8 bw = frag(sW, lm, kb);
      Macc  = __builtin_amdgcn_mfma_f32_16x16x32_bf16(ak, bw, Macc, 0, 0, 0);
      Mqacc = __builtin_amdgcn_mfma_f32_16x16x32_bf16(aq, bw, Mqacc, 0, 0, 0);
    }
    // K-transpose read: thread -> row t = ln, cols d0..d0+15 (d0 = wv*16)
    int d0 = wv*16;
    uint4 kr0 = *(const uint4*)(sK + ln*64 + SWZ(ln, d0));
    uint4 kr1 = *(const uint4*)(sK + ln*64 + SWZ(ln, d0+8));
    // X = V - M; scatter X^T into sX
    #pragma unroll
    for (int rr = 0; rr < 4; ++rr){
      int t = wv*16 + quad*4 + rr;
      float x = bf2f(sV[t*16 + lm]) - Macc[rr];
      sX[lm*64 + SWZ(lm, t)] = f2bf(x);
    }
    // scatter K^T into sKT (per e: whole wave writes one row d)
    {
      const unsigned short* k0p = (const unsigned short*)&kr0;
      const unsigned short* k1p = (const unsigned short*)&kr1;
      #pragma unroll
      for (int e = 0; e < 8; ++e){
        int d = d0 + e;
        sKT[d*64 + SWZ(d, ln)] = k0p[e];
      }
      #pragma unroll
      for (int e = 0; e < 8; ++e){
        int d = d0 + 8 + e;
        sKT[d*64 + SWZ(d, ln)] = k1p[e];
      }
    }
    __syncthreads();   // sX, sKT ready

    // phase1: Delta[t,r] = D X  (A = D rows t, B = X^T rows r)
    f32x4 Dacc = {0,0,0,0};
    #pragma unroll
    for (int s = 0; s < 2; ++s){
      int kb = s*32 + quad*8;
      bf16x8 ad = frag(sD, wv*16+lm, kb);
      bf16x8 bx = frag(sX, lm, kb);
      Dacc = __builtin_amdgcn_mfma_f32_16x16x32_bf16(ad, bx, Dacc, 0, 0, 0);
    }
    #pragma unroll
    for (int rr = 0; rr < 4; ++rr){
      int t = wv*16 + quad*4 + rr;
      sDT[lm*64 + SWZ(lm, t)] = f2bf(Dacc[rr]);
    }
    __syncthreads();   // sDT ready

    // phase2: O = Mq + Bq Delta ; W += Delta^T K
    f32x4 Oacc = Mqacc;
    #pragma unroll
    for (int s = 0; s < 2; ++s){
      int kb = s*32 + quad*8;
      bf16x8 ab = frag(sB, wv*16+lm, kb);
      bf16x8 bd = frag(sDT, lm, kb);
      Oacc = __builtin_amdgcn_mfma_f32_16x16x32_bf16(ab, bd, Oacc, 0, 0, 0);
      bf16x8 adt = frag(sDT, lm, kb);
      bf16x8 bkt = frag(sKT, wv*16+lm, kb);
      Wacc = __builtin_amdgcn_mfma_f32_16x16x32_bf16(adt, bkt, Wacc, 0, 0, 0);
    }
    #pragma unroll
    for (int rr = 0; rr < 4; ++rr){
      int tabs = ch*CHK + wv*16 + quad*4 + rr;
      float sz = (rr==0)?sz0:(rr==1)?sz1:(rr==2)?sz2:sz3;
      lo[lobase + (size_t)tabs*(BSZ*DMODEL) + lm] = f2bf(Oacc[rr] * sz);
    }
    __syncthreads();   // all LDS reads of this chunk done

    if (ch + 1 < NCH) dma_chunk(ch + 1);
    // spill W strip (rows r = quad*4+rr, cols d = wv*16+lm)
    #pragma unroll
    for (int rr = 0; rr < 4; ++rr){
      int r = quad*4 + rr, d = wv*16 + lm;
      sW[r*64 + SWZ(r, d)] = f2bf(Wacc[rr]);
    }
  }
}

// ------------------------------------------------------------------ residual + layernorm
__global__ __launch_bounds__(256) void ln_kernel(
    const float* __restrict__ hin, const float* __restrict__ attn,
    const float* __restrict__ g, const float* __restrict__ bta,
    float* __restrict__ out){
  int row = blockIdx.x, tid = threadIdx.x;
  size_t rb = (size_t)row * DMODEL;
  float4 hv = ((const float4*)(hin + rb))[tid];
  float4 av = ((const float4*)(attn + rb))[tid];
  float4 x;
  x.x = hv.x + av.x; x.y = hv.y + av.y; x.z = hv.z + av.z; x.w = hv.w + av.w;
  float s  = x.x + x.y + x.z + x.w;
  float ss = x.x*x.x + x.y*x.y + x.z*x.z + x.w*x.w;
  #pragma unroll
  for (int off = 1; off < 64; off <<= 1){
    s  += __shfl_xor(s , off, 64);
    ss += __shfl_xor(ss, off, 64);
  }
  __shared__ float ls[4], lq[4];
  int wv = tid >> 6, ln = tid & 63;
  if (ln == 0){ ls[wv] = s; lq[wv] = ss; }
  __syncthreads();
  s  = ls[0] + ls[1] + ls[2] + ls[3];
  ss = lq[0] + lq[1] + lq[2] + lq[3];
  float mu  = s * (1.f/DMODEL);
  float var = ss * (1.f/DMODEL) - mu*mu;
  float rstd = rsqrtf(var + EPSV);
  float4 gv = ((const float4*)g)[tid], bv = ((const float4*)bta)[tid];
  float4 o;
  o.x = (x.x-mu)*rstd*gv.x + bv.x;
  o.y = (x.y-mu)*rstd*gv.y + bv.y;
  o.z = (x.z-mu)*rstd*gv.z + bv.z;
  o.w = (x.w-mu)*rstd*gv.w + bv.w;
  ((float4*)(out + rb))[tid] = o;
}

// ------------------------------------------------------------------ launch
extern "C" void kernel_launch(void* const* d_in, const int* in_sizes, int n_in,
                              void* d_out, int out_size, void* d_ws, size_t ws_size,
                              hipStream_t stream){
  const float* h     = (const float*)d_in[0];
  const float* wqkvb = (const float*)d_in[1];
  const float* wo    = (const float*)d_in[2];
  const float* lng   = (const float*)d_in[3];
  const float* lnb   = (const float*)d_in[4];
  float* out = (float*)d_out;

  char* w = (char*)d_ws;
  auto take = [&](size_t bytes)->char*{
    char* p = w; w += (bytes + 255) & ~(size_t)255; return p;
  };
  unsigned short* h_bf    = (unsigned short*)take((size_t)MROWS*DMODEL*2);
  unsigned short* wq_bf   = (unsigned short*)take((size_t)NQPAD*DMODEL*2);
  unsigned short* wo_bf   = (unsigned short*)take((size_t)DMODEL*DMODEL*2);
  unsigned short* qkvb_bf = (unsigned short*)take((size_t)MROWS*NQPAD*2);
  float* qb   = (float*)take((size_t)MROWS*DMODEL*4 + 4096);
  float* kb   = (float*)take((size_t)MROWS*DMODEL*4 + 4096);
  float* Ab   = (float*)take((size_t)MROWS*DMODEL*4);   // aliased: D+Bq after kden; attn after chunk
  float4* scal = (float4*)take((size_t)64*SLEN*16 + 4096);
  unsigned short* lo_bf = (unsigned short*)take((size_t)MROWS*DMODEL*2);
  float* Sseg = (float*)take((size_t)64*NSEG*64*4);
  unsigned short* kb16 = (unsigned short*)take((size_t)MROWS*DMODEL*2);
  unsigned short* qb16 = (unsigned short*)take((size_t)MROWS*DMODEL*2);
  unsigned short* vb16 = (unsigned short*)take((size_t)MROWS*DMODEL*2);
  unsigned short* Dg = (unsigned short*)Ab;
  unsigned short* Bg = (unsigned short*)Ab + (size_t)64*NCH*4096;
  float* attn = Ab;

  cast_bf16_kernel<<<2048, 256, 0, stream>>>(h,     h_bf,  MROWS*DMODEL/4);
  cast_bf16_kernel<<<1024, 256, 0, stream>>>(wqkvb, wq_bf, NQKVB*DMODEL/4);
  cast_bf16_kernel<<<512,  256, 0, stream>>>(wo,    wo_bf, DMODEL*DMODEL/4);

  gemm_big_kernel<true><<<dim3(MROWS/128, NQPAD/128), 256, 0, stream>>>(
      h_bf, wq_bf, qkvb_bf, MROWS, NQPAD, DMODEL);

  prep_kernel<<<MROWS*NHEAD/4, 256, 0, stream>>>(qkvb_bf, qb, kb, qb16, vb16, scal);
  segsum_kernel<<<dim3(64, NSEG), 64, 0, stream>>>(kb, Sseg);
  scan_kernel<<<dim3(64, NSEG), 64, 0, stream>>>(kb, Sseg, Ab);
  kden_kernel<<<64*SLEN/4, 256, 0, stream>>>(Ab, kb, qb, kb16, scal);
  precomp_kernel<<<64*NCH, 64, 0, stream>>>(kb16, qb16, scal, Dg, Bg);
  chunk_kernel<<<dim3(64, 4), 256, 0, stream>>>(kb16, qb16, vb16, Dg, Bg, scal, lo_bf);

  gemm_big_kernel<false><<<dim3(MROWS/128, DMODEL/128), 256, 0, stream>>>(
      lo_bf, wo_bf, attn, MROWS, DMODEL, DMODEL);

  ln_kernel<<<MROWS, 256, 0, stream>>>(h, attn, lng, lnb, out);
  (void)in_sizes; (void)n_in; (void)out_size; (void)ws_size;
}